// Round 2
// baseline (393.474 us; speedup 1.0000x reference)
//
#include <hip/hip_runtime.h>
#include <cstdint>
#include <cstddef>

// Problem constants
#define SS_ 256
#define LL_ 4
#define HH_ 1024

// ws layout (in floats)
#define ZF_OFF   ((size_t)0)                        // [2][64][4][256] = 131072 (all-zero-row flags)
#define PA_OFF   ((size_t)131072)                   // [shalf2][t2][64][4][1024] = 1048576
#define DEN_OFF  ((size_t)(131072 + 1048576))       // [shalf2][t2][64][4] = 1024

// ---------------------------------------------------------------------------
// Main fused kernel: layernorm + score + exp + online pooled accumulation.
// grid = 1024: idx = (t<<9) | (b<<3) | (l<<1) | shalf ; block = 512 (8 waves)
// Each wave owns 16 rows. Merged reduction: one 6-deep shfl chain per row
// reduces {sum v, sum v^2, sum v*p} together; dot uses d = (s3 - m*sump).
// 2-row pairs with software prefetch (4 row buffers) keep HBM in flight
// during the reduce chains.
// MODE 0: normal pass (assumes mask==1, records all-zero flags).
// MODE 1: fixup pass; recomputes first-zero index from flags, early-exit if
//         the mask is all-ones for this (t,b) (true for this data).
// ---------------------------------------------------------------------------
template <int MODE>
__global__ __launch_bounds__(512, 4) void attn_pool(const float* __restrict__ A_,
                                                    const float* __restrict__ B_,
                                                    const float* __restrict__ P_,
                                                    float* __restrict__ ws) {
  int idx = blockIdx.x;
  int shalf = idx & 1;
  int l = (idx >> 1) & 3;
  int bb = (idx >> 3) & 63;
  int t = idx >> 9;
  int tid = threadIdx.x;
  int wid = tid >> 6;
  int ln = tid & 63;

  __shared__ float pshare[1024];
  __shared__ float sm[8 * 1024];
  __shared__ int wmin[8];

  int fz = SS_;
  if (MODE == 1) {
    int myfz = SS_;
    if (tid < SS_) {
      const float* zfb = ws + ZF_OFF + ((size_t)t * 64 + bb) * 4 * SS_;
      bool az = (zfb[0 * SS_ + tid] != 0.f) && (zfb[1 * SS_ + tid] != 0.f) &&
                (zfb[2 * SS_ + tid] != 0.f) && (zfb[3 * SS_ + tid] != 0.f);
      myfz = az ? tid : SS_;
    }
#pragma unroll
    for (int off = 32; off > 0; off >>= 1) myfz = min(myfz, __shfl_xor(myfz, off));
    if (ln == 0) wmin[wid] = myfz;
    __syncthreads();
#pragma unroll
    for (int w = 0; w < 8; ++w) fz = min(fz, wmin[w]);
    if (fz >= SS_) return;  // mask all-ones: keep pass-0 result
    __syncthreads();
  }

  const float* __restrict__ X = t ? B_ : A_;

  // stage p[b,l,:] into LDS
  if (tid < 256) {
    reinterpret_cast<float4*>(pshare)[tid] =
        reinterpret_cast<const float4*>(P_ + ((size_t)bb * LL_ + l) * HH_)[tid];
  }
  __syncthreads();

  // sum of p over H (lane-uniform after reduce)
  float sump = 0.f;
  {
    const float4 pw0 = *reinterpret_cast<const float4*>(&pshare[(0 * 64 + ln) * 4]);
    const float4 pw1 = *reinterpret_cast<const float4*>(&pshare[(1 * 64 + ln) * 4]);
    const float4 pw2 = *reinterpret_cast<const float4*>(&pshare[(2 * 64 + ln) * 4]);
    const float4 pw3 = *reinterpret_cast<const float4*>(&pshare[(3 * 64 + ln) * 4]);
    sump = (pw0.x + pw0.y + pw0.z + pw0.w) + (pw1.x + pw1.y + pw1.z + pw1.w) +
           (pw2.x + pw2.y + pw2.z + pw2.w) + (pw3.x + pw3.y + pw3.z + pw3.w);
#pragma unroll
    for (int off = 32; off > 0; off >>= 1) sump += __shfl_xor(sump, off);
  }

  const float* base = X + (((size_t)bb * SS_ + (size_t)shalf * 128) * LL_ + l) * HH_;
  float* zfp = ws + ZF_OFF + (((size_t)t * 64 + bb) * 4 + l) * SS_;

  float acc[16];
#pragma unroll
  for (int j = 0; j < 16; ++j) acc[j] = 0.f;
  float den = 0.f, cm = 0.f;

  auto loadRow = [&](float (&dst)[16], int sl) {
    const float4* rp = reinterpret_cast<const float4*>(base + (size_t)sl * (LL_ * HH_));
    float4 v0 = rp[ln], v1 = rp[64 + ln], v2 = rp[128 + ln], v3 = rp[192 + ln];
    dst[0] = v0.x;  dst[1] = v0.y;  dst[2] = v0.z;  dst[3] = v0.w;
    dst[4] = v1.x;  dst[5] = v1.y;  dst[6] = v1.z;  dst[7] = v1.w;
    dst[8] = v2.x;  dst[9] = v2.y;  dst[10] = v2.z; dst[11] = v2.w;
    dst[12] = v3.x; dst[13] = v3.y; dst[14] = v3.z; dst[15] = v3.w;
  };

  auto processPair = [&](const float (&u)[16], const float (&v)[16], int slu, int slv) {
    float a1 = 0.f, a2 = 0.f, a3 = 0.f, b1 = 0.f, b2 = 0.f, b3 = 0.f;
#pragma unroll
    for (int k = 0; k < 4; ++k) {
      const float4 pw = *reinterpret_cast<const float4*>(&pshare[(k * 64 + ln) * 4]);
      a1 += u[4 * k + 0] + u[4 * k + 1] + u[4 * k + 2] + u[4 * k + 3];
      a2 = fmaf(u[4 * k + 0], u[4 * k + 0], fmaf(u[4 * k + 1], u[4 * k + 1],
           fmaf(u[4 * k + 2], u[4 * k + 2], fmaf(u[4 * k + 3], u[4 * k + 3], a2))));
      a3 = fmaf(u[4 * k + 0], pw.x, fmaf(u[4 * k + 1], pw.y,
           fmaf(u[4 * k + 2], pw.z, fmaf(u[4 * k + 3], pw.w, a3))));
      b1 += v[4 * k + 0] + v[4 * k + 1] + v[4 * k + 2] + v[4 * k + 3];
      b2 = fmaf(v[4 * k + 0], v[4 * k + 0], fmaf(v[4 * k + 1], v[4 * k + 1],
           fmaf(v[4 * k + 2], v[4 * k + 2], fmaf(v[4 * k + 3], v[4 * k + 3], b2))));
      b3 = fmaf(v[4 * k + 0], pw.x, fmaf(v[4 * k + 1], pw.y,
           fmaf(v[4 * k + 2], pw.z, fmaf(v[4 * k + 3], pw.w, b3))));
    }
#pragma unroll
    for (int off = 32; off > 0; off >>= 1) {
      a1 += __shfl_xor(a1, off); a2 += __shfl_xor(a2, off); a3 += __shfl_xor(a3, off);
      b1 += __shfl_xor(b1, off); b2 += __shfl_xor(b2, off); b3 += __shfl_xor(b3, off);
    }
    // row u
    {
      float m_ = a1 * (1.f / 1024.f);
      float var_ = fmaf(-m_, m_, a2 * (1.f / 1024.f));
      float rstd_ = rsqrtf(var_ + 1e-5f);
      float d_ = (a3 - m_ * sump) * rstd_ * 0.03125f;
      float e_ = expf(d_);
      int sg_ = shalf * 128 + slu;
      if (MODE == 0) {
        if (ln == 0) zfp[sg_] = (a2 == 0.f) ? 1.f : 0.f;
      } else {
        if (sg_ >= fz) e_ = 0.f;
      }
      float coef_ = e_ * rstd_;
#pragma unroll
      for (int j = 0; j < 16; ++j) acc[j] = fmaf(coef_, u[j], acc[j]);
      cm = fmaf(coef_, m_, cm);
      den += e_;
    }
    // row v
    {
      float m_ = b1 * (1.f / 1024.f);
      float var_ = fmaf(-m_, m_, b2 * (1.f / 1024.f));
      float rstd_ = rsqrtf(var_ + 1e-5f);
      float d_ = (b3 - m_ * sump) * rstd_ * 0.03125f;
      float e_ = expf(d_);
      int sg_ = shalf * 128 + slv;
      if (MODE == 0) {
        if (ln == 0) zfp[sg_] = (b2 == 0.f) ? 1.f : 0.f;
      } else {
        if (sg_ >= fz) e_ = 0.f;
      }
      float coef_ = e_ * rstd_;
#pragma unroll
      for (int j = 0; j < 16; ++j) acc[j] = fmaf(coef_, v[j], acc[j]);
      cm = fmaf(coef_, m_, cm);
      den += e_;
    }
  };

  float xa[16], xb[16], ya[16], yb[16];
  loadRow(xa, wid + 0);   loadRow(xb, wid + 8);
  loadRow(ya, wid + 16);  loadRow(yb, wid + 24);
  processPair(xa, xb, wid + 0, wid + 8);
  loadRow(xa, wid + 32);  loadRow(xb, wid + 40);
  processPair(ya, yb, wid + 16, wid + 24);
  loadRow(ya, wid + 48);  loadRow(yb, wid + 56);
  processPair(xa, xb, wid + 32, wid + 40);
  loadRow(xa, wid + 64);  loadRow(xb, wid + 72);
  processPair(ya, yb, wid + 48, wid + 56);
  loadRow(ya, wid + 80);  loadRow(yb, wid + 88);
  processPair(xa, xb, wid + 64, wid + 72);
  loadRow(xa, wid + 96);  loadRow(xb, wid + 104);
  processPair(ya, yb, wid + 80, wid + 88);
  loadRow(ya, wid + 112); loadRow(yb, wid + 120);
  processPair(xa, xb, wid + 96, wid + 104);
  processPair(ya, yb, wid + 112, wid + 120);

  // fold the mean-shift correction into acc: pa_j = sum coef*v_j - sum coef*m
#pragma unroll
  for (int j = 0; j < 16; ++j) acc[j] -= cm;

  // combine 8 wave-partials via LDS
#pragma unroll
  for (int k = 0; k < 4; ++k) {
#pragma unroll
    for (int j = 0; j < 4; ++j) sm[wid * 1024 + (k * 64 + ln) * 4 + j] = acc[4 * k + j];
  }
  __syncthreads();
  float* pa = ws + PA_OFF + ((((size_t)shalf * 2 + t) * 64 + bb) * 4 + l) * HH_;
  for (int e2 = tid; e2 < 1024; e2 += 512) {
    float tot = 0.f;
#pragma unroll
    for (int w = 0; w < 8; ++w) tot += sm[w * 1024 + e2];
    pa[e2] = tot;
  }
  __syncthreads();
  if (ln == 0) sm[wid] = den;
  __syncthreads();
  if (tid == 0) {
    float dd = 0.f;
#pragma unroll
    for (int w = 0; w < 8; ++w) dd += sm[w];
    ws[DEN_OFF + (((size_t)shalf * 2 + t) * 64 + bb) * 4 + l] = dd;
  }
}

// ---------------------------------------------------------------------------
// Merged head + out: per b, compute y[b, l*16+o] for all l, then BN+ReLU,
// tanh encodings and the final 66x3 matvec. grid = 64 (b), block = 256.
// ---------------------------------------------------------------------------
__global__ __launch_bounds__(256) void headout_kernel(
    const float* __restrict__ p, const float* __restrict__ fw, const float* __restrict__ fb,
    const float* __restrict__ ap, const float* __restrict__ bp,
    const float* __restrict__ gam, const float* __restrict__ bet,
    const float* __restrict__ rm, const float* __restrict__ rv,
    const float* __restrict__ msw, const float* __restrict__ msb,
    const float* __restrict__ dw, const float* __restrict__ db,
    const float* __restrict__ ws, float* __restrict__ out) {
  int bb = blockIdx.x;
  int t = threadIdx.x;
  __shared__ float red[256 * 17 + 16 * 17];
  __shared__ float yv[64];
  const float* den = ws + DEN_OFF;

  for (int l = 0; l < 4; ++l) {
    float inv_a = 1.0f / (den[((0 * 2 + 0) * 64 + bb) * 4 + l] +
                          den[((1 * 2 + 0) * 64 + bb) * 4 + l] + 1e-15f);
    float inv_b = 1.0f / (den[((0 * 2 + 1) * 64 + bb) * 4 + l] +
                          den[((1 * 2 + 1) * 64 + bb) * 4 + l] + 1e-15f);

    const float4* pa00 = reinterpret_cast<const float4*>(ws + PA_OFF + (((size_t)(0 * 2 + 0) * 64 + bb) * 4 + l) * HH_);
    const float4* pa10 = reinterpret_cast<const float4*>(ws + PA_OFF + (((size_t)(1 * 2 + 0) * 64 + bb) * 4 + l) * HH_);
    const float4* pb01 = reinterpret_cast<const float4*>(ws + PA_OFF + (((size_t)(0 * 2 + 1) * 64 + bb) * 4 + l) * HH_);
    const float4* pb11 = reinterpret_cast<const float4*>(ws + PA_OFF + (((size_t)(1 * 2 + 1) * 64 + bb) * 4 + l) * HH_);

    float4 pv = reinterpret_cast<const float4*>(p + ((size_t)bb * LL_ + l) * HH_)[t];
    float4 A0 = pa00[t], A1 = pa10[t], B0 = pb01[t], B1 = pb11[t];
    float av[4] = {(A0.x + A1.x) * inv_a, (A0.y + A1.y) * inv_a,
                   (A0.z + A1.z) * inv_a, (A0.w + A1.w) * inv_a};
    float bv[4] = {(B0.x + B1.x) * inv_b, (B0.y + B1.y) * inv_b,
                   (B0.z + B1.z) * inv_b, (B0.w + B1.w) * inv_b};
    float cp[4] = {pv.x, pv.y, pv.z, pv.w};

    float part[16];
#pragma unroll
    for (int o = 0; o < 16; ++o) part[o] = 0.f;

    const float* wl = fw + (size_t)l * 5120 * 16;
#pragma unroll
    for (int j = 0; j < 4; ++j) {
      int h = t * 4 + j;
      float c[5] = {cp[j], av[j], bv[j], cp[j] * av[j], cp[j] * bv[j]};
#pragma unroll
      for (int sec = 0; sec < 5; ++sec) {
        const float4* wr = reinterpret_cast<const float4*>(wl + ((size_t)sec * 1024 + h) * 16);
#pragma unroll
        for (int o4 = 0; o4 < 4; ++o4) {
          float4 w4 = wr[o4];
          part[o4 * 4 + 0] += c[sec] * w4.x;
          part[o4 * 4 + 1] += c[sec] * w4.y;
          part[o4 * 4 + 2] += c[sec] * w4.z;
          part[o4 * 4 + 3] += c[sec] * w4.w;
        }
      }
    }

#pragma unroll
    for (int o = 0; o < 16; ++o) red[t * 17 + o] = part[o];
    __syncthreads();
    {
      int o = t & 15, g = t >> 4;
      float sacc = 0.f;
#pragma unroll
      for (int i = 0; i < 16; ++i) sacc += red[(g * 16 + i) * 17 + o];
      red[256 * 17 + g * 17 + o] = sacc;
    }
    __syncthreads();
    if (t < 16) {
      float sacc = 0.f;
#pragma unroll
      for (int g = 0; g < 16; ++g) sacc += red[256 * 17 + g * 17 + t];
      yv[l * 16 + t] = sacc + fb[l * 16 + t];
    }
    __syncthreads();
  }

  if (t < 64) {
    int k = t;
    float y = yv[k];
    y = (y - rm[k]) * rsqrtf(rv[k] + 1e-5f) * gam[k] + bet[k];
    y = fmaxf(y, 0.f);
    float w0 = dw[0], b0 = db[0];
    float ape = tanhf(ap[bb] * w0 + b0);
    float bpe = tanhf(bp[bb] * w0 + b0);
#pragma unroll
    for (int c = 0; c < 3; ++c) {
      float v = y * msw[k * 3 + c];
#pragma unroll
      for (int off = 32; off > 0; off >>= 1) v += __shfl_xor(v, off);
      if (k == 0) out[bb * 3 + c] = v + ape * msw[64 * 3 + c] + bpe * msw[65 * 3 + c] + msb[c];
    }
  }
}

extern "C" void kernel_launch(void* const* d_in, const int* in_sizes, int n_in,
                              void* d_out, int out_size, void* d_ws, size_t ws_size,
                              hipStream_t stream) {
  (void)in_sizes; (void)n_in; (void)out_size; (void)ws_size;
  const float* a = (const float*)d_in[0];
  const float* b = (const float*)d_in[1];
  const float* p = (const float*)d_in[2];
  const float* ap = (const float*)d_in[3];
  const float* bp = (const float*)d_in[4];
  const float* ffnn_w = (const float*)d_in[5];
  const float* ffnn_b = (const float*)d_in[6];
  const float* bn_g = (const float*)d_in[7];
  const float* bn_b = (const float*)d_in[8];
  const float* bn_rm = (const float*)d_in[9];
  const float* bn_rv = (const float*)d_in[10];
  const float* ms_w = (const float*)d_in[11];
  const float* ms_b = (const float*)d_in[12];
  const float* dist_w = (const float*)d_in[13];
  const float* dist_b = (const float*)d_in[14];
  float* ws = (float*)d_ws;
  float* out = (float*)d_out;

  hipLaunchKernelGGL((attn_pool<0>), dim3(1024), dim3(512), 0, stream, a, b, p, ws);
  hipLaunchKernelGGL((attn_pool<1>), dim3(1024), dim3(512), 0, stream, a, b, p, ws);
  hipLaunchKernelGGL(headout_kernel, dim3(64), dim3(256), 0, stream,
                     p, ffnn_w, ffnn_b, ap, bp, bn_g, bn_b, bn_rm, bn_rv,
                     ms_w, ms_b, dist_w, dist_b, ws, out);
}

// Round 3
// 276.565 us; speedup vs baseline: 1.4227x; 1.4227x over previous
//
#include <hip/hip_runtime.h>
#include <cstdint>
#include <cstddef>

// Problem constants
#define SS_ 256
#define LL_ 4
#define HH_ 1024

// ws layout (in floats)
#define ZF_OFF   ((size_t)0)                        // [2][64][4][256] = 131072 (all-zero-row flags)
#define PA_OFF   ((size_t)131072)                   // [shalf2][t2][64][4][1024] = 1048576
#define DEN_OFF  ((size_t)(131072 + 1048576))       // [shalf2][t2][64][4] = 1024

// ---------------------------------------------------------------------------
// Main fused kernel: layernorm + score + exp + online pooled accumulation.
// grid = 1024: idx = (t<<9) | (b<<3) | (l<<1) | shalf ; block = 512 (8 waves)
// Each wave owns 16 rows (s = r*8 + wid). Per row, ONE 6-level shfl chain
// reduces {sum v, sum v^2, sum v*p} together; dot via d = (s3 - m*sump).
// TWO register row buffers ping-pong so the next row's 4x1KB global loads
// stay in flight during the current row's reduce chain (latency -> BW bound).
// p lives in LDS (frees 16 VGPRs; read per-row as float4s).
// MODE 0: normal pass (assumes mask==1, records all-zero flags).
// MODE 1: fixup pass; recomputes first-zero index from flags, early-exit if
//         the mask is all-ones for this (t,b) (true for this data).
// ---------------------------------------------------------------------------
template <int MODE>
__global__ __launch_bounds__(512) void attn_pool(const float* __restrict__ A_,
                                                 const float* __restrict__ B_,
                                                 const float* __restrict__ P_,
                                                 float* __restrict__ ws) {
  int idx = blockIdx.x;
  int shalf = idx & 1;
  int l = (idx >> 1) & 3;
  int bb = (idx >> 3) & 63;
  int t = idx >> 9;
  int tid = threadIdx.x;
  int wid = tid >> 6;
  int ln = tid & 63;

  __shared__ float pshare[1024];
  __shared__ float sm[8 * 1024];
  __shared__ int wmin[8];

  int fz = SS_;
  if (MODE == 1) {
    int myfz = SS_;
    if (tid < SS_) {
      const float* zfb = ws + ZF_OFF + ((size_t)t * 64 + bb) * 4 * SS_;
      bool az = (zfb[0 * SS_ + tid] != 0.f) && (zfb[1 * SS_ + tid] != 0.f) &&
                (zfb[2 * SS_ + tid] != 0.f) && (zfb[3 * SS_ + tid] != 0.f);
      myfz = az ? tid : SS_;
    }
#pragma unroll
    for (int off = 32; off > 0; off >>= 1) myfz = min(myfz, __shfl_xor(myfz, off));
    if (ln == 0) wmin[wid] = myfz;
    __syncthreads();
#pragma unroll
    for (int w = 0; w < 8; ++w) fz = min(fz, wmin[w]);
    if (fz >= SS_) return;  // mask all-ones: keep pass-0 result
    __syncthreads();
  }

  const float* __restrict__ X = t ? B_ : A_;

  // stage p[b,l,:] into LDS
  if (tid < 256) {
    reinterpret_cast<float4*>(pshare)[tid] =
        reinterpret_cast<const float4*>(P_ + ((size_t)bb * LL_ + l) * HH_)[tid];
  }
  __syncthreads();

  // sum of p over H (lane-uniform after reduce)
  float sump = 0.f;
  {
#pragma unroll
    for (int k = 0; k < 4; ++k) {
      const float4 pw = *reinterpret_cast<const float4*>(&pshare[(k * 64 + ln) * 4]);
      sump += (pw.x + pw.y) + (pw.z + pw.w);
    }
#pragma unroll
    for (int off = 32; off > 0; off >>= 1) sump += __shfl_xor(sump, off);
  }

  const float* base = X + (((size_t)bb * SS_ + (size_t)shalf * 128) * LL_ + l) * HH_;
  float* zfp = ws + ZF_OFF + (((size_t)t * 64 + bb) * 4 + l) * SS_;

  float acc[16];
#pragma unroll
  for (int j = 0; j < 16; ++j) acc[j] = 0.f;
  float den = 0.f, cm = 0.f;

  auto loadRow = [&](float (&dst)[16], int sl) {
    const float4* rp = reinterpret_cast<const float4*>(base + (size_t)sl * (LL_ * HH_));
    float4 v0 = rp[ln], v1 = rp[64 + ln], v2 = rp[128 + ln], v3 = rp[192 + ln];
    dst[0] = v0.x;  dst[1] = v0.y;  dst[2] = v0.z;  dst[3] = v0.w;
    dst[4] = v1.x;  dst[5] = v1.y;  dst[6] = v1.z;  dst[7] = v1.w;
    dst[8] = v2.x;  dst[9] = v2.y;  dst[10] = v2.z; dst[11] = v2.w;
    dst[12] = v3.x; dst[13] = v3.y; dst[14] = v3.z; dst[15] = v3.w;
  };

  auto processRow = [&](const float (&u)[16], int sl) {
    float s1 = 0.f, s2 = 0.f, s3 = 0.f;
#pragma unroll
    for (int k = 0; k < 4; ++k) {
      const float4 pw = *reinterpret_cast<const float4*>(&pshare[(k * 64 + ln) * 4]);
      s1 += (u[4 * k + 0] + u[4 * k + 1]) + (u[4 * k + 2] + u[4 * k + 3]);
      s2 = fmaf(u[4 * k + 0], u[4 * k + 0], fmaf(u[4 * k + 1], u[4 * k + 1],
           fmaf(u[4 * k + 2], u[4 * k + 2], fmaf(u[4 * k + 3], u[4 * k + 3], s2))));
      s3 = fmaf(u[4 * k + 0], pw.x, fmaf(u[4 * k + 1], pw.y,
           fmaf(u[4 * k + 2], pw.z, fmaf(u[4 * k + 3], pw.w, s3))));
    }
#pragma unroll
    for (int off = 32; off > 0; off >>= 1) {
      s1 += __shfl_xor(s1, off);
      s2 += __shfl_xor(s2, off);
      s3 += __shfl_xor(s3, off);
    }
    float m_ = s1 * (1.f / 1024.f);
    float var_ = fmaf(-m_, m_, s2 * (1.f / 1024.f));
    float rstd_ = rsqrtf(var_ + 1e-5f);
    float d_ = (s3 - m_ * sump) * rstd_ * 0.03125f;
    float e_ = __expf(d_);
    int sg_ = shalf * 128 + sl;
    if (MODE == 0) {
      if (ln == 0) zfp[sg_] = (s2 == 0.f) ? 1.f : 0.f;
    } else {
      if (sg_ >= fz) e_ = 0.f;
    }
    float coef_ = e_ * rstd_;
#pragma unroll
    for (int j = 0; j < 16; ++j) acc[j] = fmaf(coef_, u[j], acc[j]);
    cm = fmaf(coef_, m_, cm);
    den += e_;
  };

  // ping-pong: next row's loads in flight during current row's reduce chain
  float u[16], v[16];
  loadRow(u, wid);  // row r=0
#pragma unroll
  for (int r = 0; r < 15; r += 2) {
    loadRow(v, (r + 1) * 8 + wid);
    processRow(u, r * 8 + wid);
    if (r + 2 < 16) loadRow(u, (r + 2) * 8 + wid);
    processRow(v, (r + 1) * 8 + wid);
  }

  // fold the mean-shift correction into acc: pa_j = sum coef*v_j - sum coef*m
#pragma unroll
  for (int j = 0; j < 16; ++j) acc[j] -= cm;

  // combine 8 wave-partials via LDS
#pragma unroll
  for (int k = 0; k < 4; ++k) {
#pragma unroll
    for (int j = 0; j < 4; ++j) sm[wid * 1024 + (k * 64 + ln) * 4 + j] = acc[4 * k + j];
  }
  __syncthreads();
  float* pa = ws + PA_OFF + ((((size_t)shalf * 2 + t) * 64 + bb) * 4 + l) * HH_;
  for (int e2 = tid; e2 < 1024; e2 += 512) {
    float tot = 0.f;
#pragma unroll
    for (int w = 0; w < 8; ++w) tot += sm[w * 1024 + e2];
    pa[e2] = tot;
  }
  __syncthreads();
  if (ln == 0) sm[wid] = den;
  __syncthreads();
  if (tid == 0) {
    float dd = 0.f;
#pragma unroll
    for (int w = 0; w < 8; ++w) dd += sm[w];
    ws[DEN_OFF + (((size_t)shalf * 2 + t) * 64 + bb) * 4 + l] = dd;
  }
}

// ---------------------------------------------------------------------------
// Merged head + out: per b, compute y[b, l*16+o] for all l, then BN+ReLU,
// tanh encodings and the final 66x3 matvec. grid = 64 (b), block = 256.
// ---------------------------------------------------------------------------
__global__ __launch_bounds__(256) void headout_kernel(
    const float* __restrict__ p, const float* __restrict__ fw, const float* __restrict__ fb,
    const float* __restrict__ ap, const float* __restrict__ bp,
    const float* __restrict__ gam, const float* __restrict__ bet,
    const float* __restrict__ rm, const float* __restrict__ rv,
    const float* __restrict__ msw, const float* __restrict__ msb,
    const float* __restrict__ dw, const float* __restrict__ db,
    const float* __restrict__ ws, float* __restrict__ out) {
  int bb = blockIdx.x;
  int t = threadIdx.x;
  __shared__ float red[256 * 17 + 16 * 17];
  __shared__ float yv[64];
  const float* den = ws + DEN_OFF;

  for (int l = 0; l < 4; ++l) {
    float inv_a = 1.0f / (den[((0 * 2 + 0) * 64 + bb) * 4 + l] +
                          den[((1 * 2 + 0) * 64 + bb) * 4 + l] + 1e-15f);
    float inv_b = 1.0f / (den[((0 * 2 + 1) * 64 + bb) * 4 + l] +
                          den[((1 * 2 + 1) * 64 + bb) * 4 + l] + 1e-15f);

    const float4* pa00 = reinterpret_cast<const float4*>(ws + PA_OFF + (((size_t)(0 * 2 + 0) * 64 + bb) * 4 + l) * HH_);
    const float4* pa10 = reinterpret_cast<const float4*>(ws + PA_OFF + (((size_t)(1 * 2 + 0) * 64 + bb) * 4 + l) * HH_);
    const float4* pb01 = reinterpret_cast<const float4*>(ws + PA_OFF + (((size_t)(0 * 2 + 1) * 64 + bb) * 4 + l) * HH_);
    const float4* pb11 = reinterpret_cast<const float4*>(ws + PA_OFF + (((size_t)(1 * 2 + 1) * 64 + bb) * 4 + l) * HH_);

    float4 pv = reinterpret_cast<const float4*>(p + ((size_t)bb * LL_ + l) * HH_)[t];
    float4 A0 = pa00[t], A1 = pa10[t], B0 = pb01[t], B1 = pb11[t];
    float av[4] = {(A0.x + A1.x) * inv_a, (A0.y + A1.y) * inv_a,
                   (A0.z + A1.z) * inv_a, (A0.w + A1.w) * inv_a};
    float bv[4] = {(B0.x + B1.x) * inv_b, (B0.y + B1.y) * inv_b,
                   (B0.z + B1.z) * inv_b, (B0.w + B1.w) * inv_b};
    float cp[4] = {pv.x, pv.y, pv.z, pv.w};

    float part[16];
#pragma unroll
    for (int o = 0; o < 16; ++o) part[o] = 0.f;

    const float* wl = fw + (size_t)l * 5120 * 16;
#pragma unroll
    for (int j = 0; j < 4; ++j) {
      int h = t * 4 + j;
      float c[5] = {cp[j], av[j], bv[j], cp[j] * av[j], cp[j] * bv[j]};
#pragma unroll
      for (int sec = 0; sec < 5; ++sec) {
        const float4* wr = reinterpret_cast<const float4*>(wl + ((size_t)sec * 1024 + h) * 16);
#pragma unroll
        for (int o4 = 0; o4 < 4; ++o4) {
          float4 w4 = wr[o4];
          part[o4 * 4 + 0] += c[sec] * w4.x;
          part[o4 * 4 + 1] += c[sec] * w4.y;
          part[o4 * 4 + 2] += c[sec] * w4.z;
          part[o4 * 4 + 3] += c[sec] * w4.w;
        }
      }
    }

#pragma unroll
    for (int o = 0; o < 16; ++o) red[t * 17 + o] = part[o];
    __syncthreads();
    {
      int o = t & 15, g = t >> 4;
      float sacc = 0.f;
#pragma unroll
      for (int i = 0; i < 16; ++i) sacc += red[(g * 16 + i) * 17 + o];
      red[256 * 17 + g * 17 + o] = sacc;
    }
    __syncthreads();
    if (t < 16) {
      float sacc = 0.f;
#pragma unroll
      for (int g = 0; g < 16; ++g) sacc += red[256 * 17 + g * 17 + t];
      yv[l * 16 + t] = sacc + fb[l * 16 + t];
    }
    __syncthreads();
  }

  if (t < 64) {
    int k = t;
    float y = yv[k];
    y = (y - rm[k]) * rsqrtf(rv[k] + 1e-5f) * gam[k] + bet[k];
    y = fmaxf(y, 0.f);
    float w0 = dw[0], b0 = db[0];
    float ape = tanhf(ap[bb] * w0 + b0);
    float bpe = tanhf(bp[bb] * w0 + b0);
#pragma unroll
    for (int c = 0; c < 3; ++c) {
      float v = y * msw[k * 3 + c];
#pragma unroll
      for (int off = 32; off > 0; off >>= 1) v += __shfl_xor(v, off);
      if (k == 0) out[bb * 3 + c] = v + ape * msw[64 * 3 + c] + bpe * msw[65 * 3 + c] + msb[c];
    }
  }
}

extern "C" void kernel_launch(void* const* d_in, const int* in_sizes, int n_in,
                              void* d_out, int out_size, void* d_ws, size_t ws_size,
                              hipStream_t stream) {
  (void)in_sizes; (void)n_in; (void)out_size; (void)ws_size;
  const float* a = (const float*)d_in[0];
  const float* b = (const float*)d_in[1];
  const float* p = (const float*)d_in[2];
  const float* ap = (const float*)d_in[3];
  const float* bp = (const float*)d_in[4];
  const float* ffnn_w = (const float*)d_in[5];
  const float* ffnn_b = (const float*)d_in[6];
  const float* bn_g = (const float*)d_in[7];
  const float* bn_b = (const float*)d_in[8];
  const float* bn_rm = (const float*)d_in[9];
  const float* bn_rv = (const float*)d_in[10];
  const float* ms_w = (const float*)d_in[11];
  const float* ms_b = (const float*)d_in[12];
  const float* dist_w = (const float*)d_in[13];
  const float* dist_b = (const float*)d_in[14];
  float* ws = (float*)d_ws;
  float* out = (float*)d_out;

  hipLaunchKernelGGL((attn_pool<0>), dim3(1024), dim3(512), 0, stream, a, b, p, ws);
  hipLaunchKernelGGL((attn_pool<1>), dim3(1024), dim3(512), 0, stream, a, b, p, ws);
  hipLaunchKernelGGL(headout_kernel, dim3(64), dim3(256), 0, stream,
                     p, ffnn_w, ffnn_b, ap, bp, bn_g, bn_b, bn_rm, bn_rv,
                     ms_w, ms_b, dist_w, dist_b, ws, out);
}

// Round 4
// 162.273 us; speedup vs baseline: 2.4248x; 1.7043x over previous
//
#include <hip/hip_runtime.h>
#include <cstdint>
#include <cstddef>

// Problem constants
#define SS_ 256
#define LL_ 4
#define HH_ 1024

// ws layout (in floats)
#define ZF_OFF   ((size_t)0)                        // [2][64][4][256] = 131072 (all-zero-row flags)
#define PA_OFF   ((size_t)131072)                   // [shalf2][t2][64][4][1024] = 1048576
#define DEN_OFF  ((size_t)(131072 + 1048576))       // [shalf2][t2][64][4] = 1024

// ---------------------------------------------------------------------------
// Main fused kernel: layernorm + score + exp + online pooled accumulation.
// grid = 1024: idx = (t<<9) | (b<<3) | (l<<1) | shalf ; block = 512 (8 waves)
// Each wave owns 16 rows (s = r*8 + wid). Round-1 structure (single row
// buffer, p in registers, no LDS in the hot loop) + ONE merged 3-value
// 6-level shfl chain per row: {sum x, sum x^2, sum x*p}; the attention dot
// is d = (s3 - m*sump)*rstd*rescale with sump reduced once at start, and
// the mean-shift folds into a scalar: pa_num = sum coef*x - sum coef*m.
// MODE 0: normal pass (assumes mask==1, records all-zero flags).
// MODE 1: fixup pass; recomputes first-zero index from flags, early-exit if
//         the mask is all-ones for this (t,b) (true for this data).
// ---------------------------------------------------------------------------
template <int MODE>
__global__ __launch_bounds__(512) void attn_pool(const float* __restrict__ A_,
                                                 const float* __restrict__ B_,
                                                 const float* __restrict__ P_,
                                                 float* __restrict__ ws) {
  int idx = blockIdx.x;
  int shalf = idx & 1;
  int l = (idx >> 1) & 3;
  int bb = (idx >> 3) & 63;
  int t = idx >> 9;
  int tid = threadIdx.x;
  int wid = tid >> 6;
  int ln = tid & 63;

  __shared__ float sm[8 * 1024];
  __shared__ int wmin[8];

  int fz = SS_;
  if (MODE == 1) {
    int myfz = SS_;
    if (tid < SS_) {
      const float* zfb = ws + ZF_OFF + ((size_t)t * 64 + bb) * 4 * SS_;
      bool az = (zfb[0 * SS_ + tid] != 0.f) && (zfb[1 * SS_ + tid] != 0.f) &&
                (zfb[2 * SS_ + tid] != 0.f) && (zfb[3 * SS_ + tid] != 0.f);
      myfz = az ? tid : SS_;
    }
#pragma unroll
    for (int off = 32; off > 0; off >>= 1) myfz = min(myfz, __shfl_xor(myfz, off));
    if (ln == 0) wmin[wid] = myfz;
    __syncthreads();
#pragma unroll
    for (int w = 0; w < 8; ++w) fz = min(fz, wmin[w]);
    if (fz >= SS_) return;  // mask all-ones: keep pass-0 result
  }

  const float* __restrict__ X = t ? B_ : A_;

  // p[b,l,:] in registers, same lane mapping as row loads
  float pv[16];
  {
    const float4* pr = reinterpret_cast<const float4*>(P_ + ((size_t)bb * LL_ + l) * HH_);
#pragma unroll
    for (int k = 0; k < 4; ++k) {
      float4 v = pr[k * 64 + ln];
      pv[4 * k + 0] = v.x; pv[4 * k + 1] = v.y;
      pv[4 * k + 2] = v.z; pv[4 * k + 3] = v.w;
    }
  }

  // sum of p over H (lane-uniform after reduce)
  float sump = 0.f;
  {
#pragma unroll
    for (int j = 0; j < 16; ++j) sump += pv[j];
#pragma unroll
    for (int off = 32; off > 0; off >>= 1) sump += __shfl_xor(sump, off);
  }

  const float* base = X + (((size_t)bb * SS_ + (size_t)shalf * 128) * LL_ + l) * HH_;
  float* zfp = ws + ZF_OFF + (((size_t)t * 64 + bb) * 4 + l) * SS_;

  float acc[16];
#pragma unroll
  for (int j = 0; j < 16; ++j) acc[j] = 0.f;
  float den = 0.f, cm = 0.f;

  for (int r = 0; r < 16; ++r) {
    int sl = r * 8 + wid;
    const float4* rp = reinterpret_cast<const float4*>(base + (size_t)sl * (LL_ * HH_));
    float x[16];
    {
      float4 v0 = rp[ln], v1 = rp[64 + ln], v2 = rp[128 + ln], v3 = rp[192 + ln];
      x[0] = v0.x;  x[1] = v0.y;  x[2] = v0.z;  x[3] = v0.w;
      x[4] = v1.x;  x[5] = v1.y;  x[6] = v1.z;  x[7] = v1.w;
      x[8] = v2.x;  x[9] = v2.y;  x[10] = v2.z; x[11] = v2.w;
      x[12] = v3.x; x[13] = v3.y; x[14] = v3.z; x[15] = v3.w;
    }
    float s1 = 0.f, s2 = 0.f, s3 = 0.f;
#pragma unroll
    for (int j = 0; j < 16; ++j) {
      s1 += x[j];
      s2 = fmaf(x[j], x[j], s2);
      s3 = fmaf(x[j], pv[j], s3);
    }
    // one merged 6-level chain for {s1,s2,s3}
#pragma unroll
    for (int off = 32; off > 0; off >>= 1) {
      s1 += __shfl_xor(s1, off);
      s2 += __shfl_xor(s2, off);
      s3 += __shfl_xor(s3, off);
    }
    float m_ = s1 * (1.f / 1024.f);
    float var_ = fmaf(-m_, m_, s2 * (1.f / 1024.f));
    float rstd_ = rsqrtf(var_ + 1e-5f);
    float d_ = (s3 - m_ * sump) * rstd_ * 0.03125f;
    float e_ = __expf(d_);
    if (MODE == 0) {
      if (ln == 0) zfp[shalf * 128 + sl] = (s2 == 0.f) ? 1.f : 0.f;
    } else {
      if (shalf * 128 + sl >= fz) e_ = 0.f;
    }
    float coef_ = e_ * rstd_;
#pragma unroll
    for (int j = 0; j < 16; ++j) acc[j] = fmaf(coef_, x[j], acc[j]);
    cm = fmaf(coef_, m_, cm);
    den += e_;
  }

  // fold the mean-shift correction into acc: pa_j = sum coef*x_j - sum coef*m
#pragma unroll
  for (int j = 0; j < 16; ++j) acc[j] -= cm;

  // combine 8 wave-partials via LDS
#pragma unroll
  for (int k = 0; k < 4; ++k) {
#pragma unroll
    for (int j = 0; j < 4; ++j) sm[wid * 1024 + (k * 64 + ln) * 4 + j] = acc[4 * k + j];
  }
  __syncthreads();
  float* pa = ws + PA_OFF + ((((size_t)shalf * 2 + t) * 64 + bb) * 4 + l) * HH_;
  for (int e2 = tid; e2 < 1024; e2 += 512) {
    float tot = 0.f;
#pragma unroll
    for (int w = 0; w < 8; ++w) tot += sm[w * 1024 + e2];
    pa[e2] = tot;
  }
  __syncthreads();
  if (ln == 0) sm[wid] = den;
  __syncthreads();
  if (tid == 0) {
    float dd = 0.f;
#pragma unroll
    for (int w = 0; w < 8; ++w) dd += sm[w];
    ws[DEN_OFF + (((size_t)shalf * 2 + t) * 64 + bb) * 4 + l] = dd;
  }
}

// ---------------------------------------------------------------------------
// Merged head + out: per b, compute y[b, l*16+o] for all l, then BN+ReLU,
// tanh encodings and the final 66x3 matvec. grid = 64 (b), block = 256.
// ---------------------------------------------------------------------------
__global__ __launch_bounds__(256) void headout_kernel(
    const float* __restrict__ p, const float* __restrict__ fw, const float* __restrict__ fb,
    const float* __restrict__ ap, const float* __restrict__ bp,
    const float* __restrict__ gam, const float* __restrict__ bet,
    const float* __restrict__ rm, const float* __restrict__ rv,
    const float* __restrict__ msw, const float* __restrict__ msb,
    const float* __restrict__ dw, const float* __restrict__ db,
    const float* __restrict__ ws, float* __restrict__ out) {
  int bb = blockIdx.x;
  int t = threadIdx.x;
  __shared__ float red[256 * 17 + 16 * 17];
  __shared__ float yv[64];
  const float* den = ws + DEN_OFF;

  for (int l = 0; l < 4; ++l) {
    float inv_a = 1.0f / (den[((0 * 2 + 0) * 64 + bb) * 4 + l] +
                          den[((1 * 2 + 0) * 64 + bb) * 4 + l] + 1e-15f);
    float inv_b = 1.0f / (den[((0 * 2 + 1) * 64 + bb) * 4 + l] +
                          den[((1 * 2 + 1) * 64 + bb) * 4 + l] + 1e-15f);

    const float4* pa00 = reinterpret_cast<const float4*>(ws + PA_OFF + (((size_t)(0 * 2 + 0) * 64 + bb) * 4 + l) * HH_);
    const float4* pa10 = reinterpret_cast<const float4*>(ws + PA_OFF + (((size_t)(1 * 2 + 0) * 64 + bb) * 4 + l) * HH_);
    const float4* pb01 = reinterpret_cast<const float4*>(ws + PA_OFF + (((size_t)(0 * 2 + 1) * 64 + bb) * 4 + l) * HH_);
    const float4* pb11 = reinterpret_cast<const float4*>(ws + PA_OFF + (((size_t)(1 * 2 + 1) * 64 + bb) * 4 + l) * HH_);

    float4 pv = reinterpret_cast<const float4*>(p + ((size_t)bb * LL_ + l) * HH_)[t];
    float4 A0 = pa00[t], A1 = pa10[t], B0 = pb01[t], B1 = pb11[t];
    float av[4] = {(A0.x + A1.x) * inv_a, (A0.y + A1.y) * inv_a,
                   (A0.z + A1.z) * inv_a, (A0.w + A1.w) * inv_a};
    float bv[4] = {(B0.x + B1.x) * inv_b, (B0.y + B1.y) * inv_b,
                   (B0.z + B1.z) * inv_b, (B0.w + B1.w) * inv_b};
    float cp[4] = {pv.x, pv.y, pv.z, pv.w};

    float part[16];
#pragma unroll
    for (int o = 0; o < 16; ++o) part[o] = 0.f;

    const float* wl = fw + (size_t)l * 5120 * 16;
#pragma unroll
    for (int j = 0; j < 4; ++j) {
      int h = t * 4 + j;
      float c[5] = {cp[j], av[j], bv[j], cp[j] * av[j], cp[j] * bv[j]};
#pragma unroll
      for (int sec = 0; sec < 5; ++sec) {
        const float4* wr = reinterpret_cast<const float4*>(wl + ((size_t)sec * 1024 + h) * 16);
#pragma unroll
        for (int o4 = 0; o4 < 4; ++o4) {
          float4 w4 = wr[o4];
          part[o4 * 4 + 0] += c[sec] * w4.x;
          part[o4 * 4 + 1] += c[sec] * w4.y;
          part[o4 * 4 + 2] += c[sec] * w4.z;
          part[o4 * 4 + 3] += c[sec] * w4.w;
        }
      }
    }

#pragma unroll
    for (int o = 0; o < 16; ++o) red[t * 17 + o] = part[o];
    __syncthreads();
    {
      int o = t & 15, g = t >> 4;
      float sacc = 0.f;
#pragma unroll
      for (int i = 0; i < 16; ++i) sacc += red[(g * 16 + i) * 17 + o];
      red[256 * 17 + g * 17 + o] = sacc;
    }
    __syncthreads();
    if (t < 16) {
      float sacc = 0.f;
#pragma unroll
      for (int g = 0; g < 16; ++g) sacc += red[256 * 17 + g * 17 + t];
      yv[l * 16 + t] = sacc + fb[l * 16 + t];
    }
    __syncthreads();
  }

  if (t < 64) {
    int k = t;
    float y = yv[k];
    y = (y - rm[k]) * rsqrtf(rv[k] + 1e-5f) * gam[k] + bet[k];
    y = fmaxf(y, 0.f);
    float w0 = dw[0], b0 = db[0];
    float ape = tanhf(ap[bb] * w0 + b0);
    float bpe = tanhf(bp[bb] * w0 + b0);
#pragma unroll
    for (int c = 0; c < 3; ++c) {
      float v = y * msw[k * 3 + c];
#pragma unroll
      for (int off = 32; off > 0; off >>= 1) v += __shfl_xor(v, off);
      if (k == 0) out[bb * 3 + c] = v + ape * msw[64 * 3 + c] + bpe * msw[65 * 3 + c] + msb[c];
    }
  }
}

extern "C" void kernel_launch(void* const* d_in, const int* in_sizes, int n_in,
                              void* d_out, int out_size, void* d_ws, size_t ws_size,
                              hipStream_t stream) {
  (void)in_sizes; (void)n_in; (void)out_size; (void)ws_size;
  const float* a = (const float*)d_in[0];
  const float* b = (const float*)d_in[1];
  const float* p = (const float*)d_in[2];
  const float* ap = (const float*)d_in[3];
  const float* bp = (const float*)d_in[4];
  const float* ffnn_w = (const float*)d_in[5];
  const float* ffnn_b = (const float*)d_in[6];
  const float* bn_g = (const float*)d_in[7];
  const float* bn_b = (const float*)d_in[8];
  const float* bn_rm = (const float*)d_in[9];
  const float* bn_rv = (const float*)d_in[10];
  const float* ms_w = (const float*)d_in[11];
  const float* ms_b = (const float*)d_in[12];
  const float* dist_w = (const float*)d_in[13];
  const float* dist_b = (const float*)d_in[14];
  float* ws = (float*)d_ws;
  float* out = (float*)d_out;

  hipLaunchKernelGGL((attn_pool<0>), dim3(1024), dim3(512), 0, stream, a, b, p, ws);
  hipLaunchKernelGGL((attn_pool<1>), dim3(1024), dim3(512), 0, stream, a, b, p, ws);
  hipLaunchKernelGGL(headout_kernel, dim3(64), dim3(256), 0, stream,
                     p, ffnn_w, ffnn_b, ap, bp, bn_g, bn_b, bn_rm, bn_rv,
                     ms_w, ms_b, dist_w, dist_b, ws, out);
}